// Round 1
// baseline (308942.700 us; speedup 1.0000x reference)
//
#include <hip/hip_runtime.h>
#include <math.h>

// Deep Reservoir Memory Network forward, MI355X persistent-dataflow kernel.
// Round 0: fp32 correctness baseline.
//
// Structure: ONE persistent kernel, 256 blocks x 512 threads. Blocks are
// pinned to fixed column-slices of the 8 recurrent weight matrices, grouped
// into 5 dataflow sets. Producer/consumer sync via device-scope (agent/sc1)
// atomic flags; recurrent state exchanged via agent-scope atomic loads/stores
// (served at the coherent LLC -> no L2-invalidating acquire fences, weights
// stay hot in per-XCD L2). States are double-buffered by tick parity.
//
// Sets (blockIdx.x):
//   [0,32)    M1 : m1_new = m1_old@Vm1^T + x_t@Wm1^T          (32 cols/blk)
//   [32,96)   M2 : m2_new = m2_old@Vm2^T + m1_new@Wm2^T       (16 cols/blk)
//   [96,160)  H1 : h1_new = .5*h1 + .5*tanh(x@Win1^T + h1@Wh1^T
//                                           + m2_new@Wmh1^T + b1)
//   [160,224) H2 : h2_new = .5*h2 + .5*tanh(g2a + h1_new@Win2^T
//                                           + m2_new@Wmh2^T)   (+ write out)
//   [224,256) G2 : g2a = h2_old@Wh2^T + b2                     (32 cols/blk)

#define BB 32
#define TT 2048
#define II 64
#define MM 1024
#define HHH 1024
#define ALEAK 0.5f
#define NTHREADS 512
#define SPIN_CAP 5000

#define SCOPE __HIP_MEMORY_SCOPE_AGENT

__device__ __forceinline__ float lda(const float* p) {
  return __hip_atomic_load(p, __ATOMIC_RELAXED, SCOPE);
}
__device__ __forceinline__ void sta(float* p, float v) {
  __hip_atomic_store(p, v, __ATOMIC_RELAXED, SCOPE);
}

// lane0 spins on a device-scope flag; capped so a sync bug can't hang the GPU.
__device__ __forceinline__ void wait_flag(int* f, int target) {
  if (threadIdx.x == 0) {
    int it = 0;
    while (__hip_atomic_load(f, __ATOMIC_RELAXED, SCOPE) < target) {
      __builtin_amdgcn_s_sleep(2);
      if (++it > SPIN_CAP) break;  // fail loud (wrong answer), not a timeout
    }
  }
  __syncthreads();
}

__device__ __forceinline__ void post_flag(int* f) {
  __syncthreads();  // drains each wave's vmcnt -> all sc1 stores at LLC
  if (threadIdx.x == 0) {
    __hip_atomic_fetch_add(f, 1, __ATOMIC_RELEASE, SCOPE);
  }
}

// Stage S[:, k0:k0+256] (32 rows) into padded LDS via coherent loads.
__device__ __forceinline__ void stage_S(float (&lds)[BB][260],
                                        const float* __restrict__ S, int k0) {
  __syncthreads();  // previous chunk's readers done
  #pragma unroll
  for (int i = 0; i < (BB * 256) / NTHREADS; ++i) {
    int idx = threadIdx.x + i * NTHREADS;
    int r = idx >> 8, kk = idx & 255;
    lds[r][kk] = lda(S + (size_t)r * MM + k0 + kk);
  }
  __syncthreads();
}

// acc += S_lds[row][0:256] . Wrow[0:256]   (Wrow already offset by k0)
__device__ __forceinline__ float dot_chunk(const float (&lds)[BB][260], int row,
                                           const float* __restrict__ Wrow) {
  float a0 = 0.f, a1 = 0.f;
  #pragma unroll 4
  for (int k = 0; k < 256; k += 8) {
    float4 wA = *(const float4*)(Wrow + k);
    float4 wB = *(const float4*)(Wrow + k + 4);
    a0 = fmaf(wA.x, lds[row][k + 0], a0);
    a0 = fmaf(wA.y, lds[row][k + 1], a0);
    a0 = fmaf(wA.z, lds[row][k + 2], a0);
    a0 = fmaf(wA.w, lds[row][k + 3], a0);
    a1 = fmaf(wB.x, lds[row][k + 4], a1);
    a1 = fmaf(wB.y, lds[row][k + 5], a1);
    a1 = fmaf(wB.z, lds[row][k + 6], a1);
    a1 = fmaf(wB.w, lds[row][k + 7], a1);
  }
  return a0 + a1;
}

// K=64 input-projection dot: x-row . Wrow (both global, cached)
__device__ __forceinline__ float dot_x(const float* __restrict__ xrow,
                                       const float* __restrict__ Wrow) {
  float a = 0.f;
  #pragma unroll
  for (int k = 0; k < II; k += 4) {
    float4 w = *(const float4*)(Wrow + k);
    float4 s = *(const float4*)(xrow + k);
    a += w.x * s.x + w.y * s.y + w.z * s.z + w.w * s.w;
  }
  return a;
}

__global__ __launch_bounds__(NTHREADS) void drmn_persistent(
    const float* __restrict__ x, const float* __restrict__ Wm1,
    const float* __restrict__ Vm1, const float* __restrict__ Wm2,
    const float* __restrict__ Vm2, const float* __restrict__ Win1,
    const float* __restrict__ Wh1, const float* __restrict__ Wmh1,
    const float* __restrict__ b1, const float* __restrict__ Win2,
    const float* __restrict__ Wh2, const float* __restrict__ Wmh2,
    const float* __restrict__ b2, float* __restrict__ out, float* ws,
    int* flags) {
  __shared__ float lds[BB][260];  // 33 KB, +4 pad breaks bank conflicts
  const int blk = blockIdx.x;
  const int tid = threadIdx.x;

  float* m1s = ws;                  // [2][B][M]
  float* m2s = m1s + 2 * BB * MM;   // [2][B][M]
  float* h1s = m2s + 2 * BB * MM;   // [2][B][H]
  float* h2s = h1s + 2 * BB * MM;   // [2][B][H]
  float* g2a = h2s + 2 * BB * MM;   // [B][H]

  int* m1c = flags;            // each [T]
  int* m2c = m1c + TT;
  int* h1c = m2c + TT;
  int* h2c = h1c + TT;
  int* g2c = h2c + TT;

  if (blk < 32) {
    // ================= M1 =================
    const int c = tid & 31, bg = tid >> 5;  // bg 0..15
    const int n = blk * 32 + c;
    const int r0 = bg, r1 = bg + 16;
    const float* wv = Vm1 + (size_t)n * MM;
    const float* wx = Wm1 + (size_t)n * II;
    for (int t = 0; t < TT; ++t) {
      const float* rd = m1s + (t & 1) * BB * MM;
      float* wr = m1s + ((t & 1) ^ 1) * BB * MM;
      if (t >= 1) wait_flag(&m1c[t - 1], 32);   // full prev state readable
      if (t >= 2) wait_flag(&m2c[t - 2], 64);   // consumer of write-buffer done
      float a0 = dot_x(x + ((size_t)r0 * TT + t) * II, wx);
      float a1 = dot_x(x + ((size_t)r1 * TT + t) * II, wx);
      for (int k0 = 0; k0 < MM; k0 += 256) {
        stage_S(lds, rd, k0);
        a0 += dot_chunk(lds, r0, wv + k0);
        a1 += dot_chunk(lds, r1, wv + k0);
      }
      sta(wr + (size_t)r0 * MM + n, a0);
      sta(wr + (size_t)r1 * MM + n, a1);
      post_flag(&m1c[t]);
    }
  } else if (blk < 96) {
    // ================= M2 =================
    const int sb = blk - 32;
    const int c = tid & 15, bg = tid >> 4;  // bg 0..31
    const int n = sb * 16 + c;
    const float* wv = Vm2 + (size_t)n * MM;
    const float* ww = Wm2 + (size_t)n * MM;
    for (int t = 0; t < TT; ++t) {
      const float* rd = m2s + (t & 1) * BB * MM;
      float* wr = m2s + ((t & 1) ^ 1) * BB * MM;
      const float* rdm1 = m1s + ((t & 1) ^ 1) * BB * MM;  // m1_new (this tick)
      if (t >= 1) wait_flag(&m2c[t - 1], 64);
      if (t >= 2) {
        wait_flag(&h1c[t - 2], 64);
        wait_flag(&h2c[t - 2], 64);
      }
      float a = 0.f;
      for (int k0 = 0; k0 < MM; k0 += 256) {
        stage_S(lds, rd, k0);
        a += dot_chunk(lds, bg, wv + k0);
      }
      wait_flag(&m1c[t], 32);
      for (int k0 = 0; k0 < MM; k0 += 256) {
        stage_S(lds, rdm1, k0);
        a += dot_chunk(lds, bg, ww + k0);
      }
      sta(wr + (size_t)bg * MM + n, a);
      post_flag(&m2c[t]);
    }
  } else if (blk < 160) {
    // ================= H1 =================
    const int sb = blk - 96;
    const int c = tid & 15, bg = tid >> 4;
    const int n = sb * 16 + c;
    const float* wh = Wh1 + (size_t)n * HHH;
    const float* wm = Wmh1 + (size_t)n * MM;
    const float* wi = Win1 + (size_t)n * II;
    const float bias = b1[n];
    float h1reg = 0.f;  // this thread's own h1[bg][n]
    for (int t = 0; t < TT; ++t) {
      const float* rdh = h1s + (t & 1) * BB * HHH;
      float* wrh = h1s + ((t & 1) ^ 1) * BB * HHH;
      const float* rdm2 = m2s + ((t & 1) ^ 1) * BB * MM;  // m2_new
      if (t >= 1) wait_flag(&h1c[t - 1], 64);
      if (t >= 2) wait_flag(&h2c[t - 2], 64);
      float a = bias + dot_x(x + ((size_t)bg * TT + t) * II, wi);
      for (int k0 = 0; k0 < HHH; k0 += 256) {
        stage_S(lds, rdh, k0);
        a += dot_chunk(lds, bg, wh + k0);
      }
      wait_flag(&m2c[t], 64);
      for (int k0 = 0; k0 < MM; k0 += 256) {
        stage_S(lds, rdm2, k0);
        a += dot_chunk(lds, bg, wm + k0);
      }
      float h1n = (1.0f - ALEAK) * h1reg + ALEAK * tanhf(a);
      h1reg = h1n;
      sta(wrh + (size_t)bg * HHH + n, h1n);
      post_flag(&h1c[t]);
    }
  } else if (blk < 224) {
    // ================= H2 main =================
    const int sb = blk - 160;
    const int c = tid & 15, bg = tid >> 4;
    const int n = sb * 16 + c;
    const float* wm = Wmh2 + (size_t)n * MM;
    const float* wi = Win2 + (size_t)n * HHH;
    float h2reg = 0.f;  // this thread's own h2[bg][n]
    for (int t = 0; t < TT; ++t) {
      float* wrh = h2s + ((t & 1) ^ 1) * BB * HHH;
      const float* rdm2 = m2s + ((t & 1) ^ 1) * BB * MM;   // m2_new
      const float* rdh1 = h1s + ((t & 1) ^ 1) * BB * HHH;  // h1_new
      wait_flag(&m2c[t], 64);
      float a = 0.f;
      for (int k0 = 0; k0 < MM; k0 += 256) {
        stage_S(lds, rdm2, k0);
        a += dot_chunk(lds, bg, wm + k0);
      }
      wait_flag(&h1c[t], 64);
      for (int k0 = 0; k0 < HHH; k0 += 256) {
        stage_S(lds, rdh1, k0);
        a += dot_chunk(lds, bg, wi + k0);
      }
      wait_flag(&g2c[t], 32);
      a += lda(g2a + (size_t)bg * HHH + n);
      float h2n = (1.0f - ALEAK) * h2reg + ALEAK * tanhf(a);
      h2reg = h2n;
      sta(wrh + (size_t)bg * HHH + n, h2n);
      out[((size_t)bg * TT + t) * HHH + n] = h2n;  // plain store; visible at kernel end
      post_flag(&h2c[t]);
    }
  } else {
    // ================= G2 (Wh2 partial) =================
    const int sb = blk - 224;
    const int c = tid & 31, bg = tid >> 5;  // bg 0..15
    const int n = sb * 32 + c;
    const int r0 = bg, r1 = bg + 16;
    const float* ww = Wh2 + (size_t)n * HHH;
    const float bias = b2[n];
    for (int t = 0; t < TT; ++t) {
      const float* rdh = h2s + (t & 1) * BB * HHH;  // h2_old
      if (t >= 1) wait_flag(&h2c[t - 1], 64);  // also: consumer of g2a done
      float a0 = bias, a1 = bias;
      for (int k0 = 0; k0 < HHH; k0 += 256) {
        stage_S(lds, rdh, k0);
        a0 += dot_chunk(lds, r0, ww + k0);
        a1 += dot_chunk(lds, r1, ww + k0);
      }
      sta(g2a + (size_t)r0 * HHH + n, a0);
      sta(g2a + (size_t)r1 * HHH + n, a1);
      post_flag(&g2c[t]);
    }
  }
}

extern "C" void kernel_launch(void* const* d_in, const int* in_sizes, int n_in,
                              void* d_out, int out_size, void* d_ws,
                              size_t ws_size, hipStream_t stream) {
  const float* xin  = (const float*)d_in[0];
  const float* Wm1  = (const float*)d_in[1];
  const float* Vm1  = (const float*)d_in[2];
  const float* Wm2  = (const float*)d_in[3];
  const float* Vm2  = (const float*)d_in[4];
  const float* Win1 = (const float*)d_in[5];
  const float* Wh1  = (const float*)d_in[6];
  const float* Wmh1 = (const float*)d_in[7];
  const float* b1   = (const float*)d_in[8];
  const float* Win2 = (const float*)d_in[9];
  const float* Wh2  = (const float*)d_in[10];
  const float* Wmh2 = (const float*)d_in[11];
  const float* b2   = (const float*)d_in[12];
  float* out = (float*)d_out;

  float* ws = (float*)d_ws;
  const size_t data_floats = (size_t)8 * BB * MM + (size_t)BB * HHH;  // states + g2a
  int* flags = (int*)(ws + data_floats);
  const size_t clear_bytes = data_floats * sizeof(float) + (size_t)5 * TT * sizeof(int);
  hipMemsetAsync(d_ws, 0, clear_bytes, stream);  // zero states + flags (ws is 0xAA-poisoned)

  drmn_persistent<<<256, NTHREADS, 0, stream>>>(
      xin, Wm1, Vm1, Wm2, Vm2, Win1, Wh1, Wmh1, b1, Win2, Wh2, Wmh2, b2, out,
      ws, flags);
}